// Round 7
// baseline (167.995 us; speedup 1.0000x reference)
//
#include <hip/hip_runtime.h>
#include <hip/hip_bf16.h>
#include <cstdint>

// Problem constants
#define NB   2
#define NC   256
#define NN   4096   // H*W = 64*64
#define NH   8      // heads
#define HSZ  32     // head size
#define NF   256    // FEAT
#define N3F  768

typedef __bf16 bf16x8 __attribute__((ext_vector_type(8)));
typedef __bf16 bf16x4 __attribute__((ext_vector_type(4)));
typedef short  s16x4  __attribute__((ext_vector_type(4)));
typedef float  floatx4 __attribute__((ext_vector_type(4)));

// log2(e)/sqrt(32): folded into q so softmax runs in exp2 domain
#define QSCALE 0.25506601622184f

// po piece stride: 16 bh x 4096 n x 32 d
#define PIECE 2097152

// direct global->LDS DMA, 16 B per lane (dest must be wave-uniform base + lane*16)
#define GLD16(gsrc, ldst)                                                             \
    __builtin_amdgcn_global_load_lds(                                                 \
        (const __attribute__((address_space(1))) unsigned int*)(gsrc),                \
        (__attribute__((address_space(3))) unsigned int*)(ldst), 16, 0, 0)

// ---------------- K0: prep = preact silu (blocks 0..255) + weight cvt (256..511) --
__global__ void k_prep(const float* __restrict__ x, const float* __restrict__ pab,
                       const float* __restrict__ pqb, __bf16* __restrict__ y,
                       const float* __restrict__ wqkv, const float* __restrict__ wproj,
                       __bf16* __restrict__ wqb, __bf16* __restrict__ wpb) {
    __shared__ __bf16 ct[32 * 264];           // [n][c], stride 264
    int bid = blockIdx.x, tid = threadIdx.x;
    if (bid >= 256) {                         // weight convert: 4 elems/thread
        int id = (bid - 256) * 1024 + tid * 4;
        const float* src = (id < 196608) ? (wqkv + id) : (wproj + (id - 196608));
        __bf16* dst = (id < 196608) ? (wqb + id) : (wpb + (id - 196608));
        float4 v = *(const float4*)src;
        bf16x4 o;
        o[0] = (__bf16)v.x; o[1] = (__bf16)v.y; o[2] = (__bf16)v.z; o[3] = (__bf16)v.w;
        *(bf16x4*)dst = o;
        return;
    }
    int b = bid >> 7, nt = bid & 127;
    int n0 = nt * 32;
    int cbase = tid >> 3, nc = tid & 7;       // n-chunk nc covers 4 n
#pragma unroll
    for (int q = 0; q < 8; q++) {
        int c = cbase + q * 32;
        const float4 xv = *(const float4*)(x + ((size_t)b * NC + c) * NN + n0 + nc * 4);
        float bias = pab[c], qb = pqb[c];
        float vs[4] = {xv.x, xv.y, xv.z, xv.w};
#pragma unroll
        for (int i = 0; i < 4; i++) {
            float s = vs[i] + bias;
            float r = s / (1.f + __expf(-s)) + qb;   // silu + pre_qkv_bias
            ct[(nc * 4 + i) * 264 + c] = (__bf16)r;
        }
    }
    __syncthreads();
#pragma unroll
    for (int q = 0; q < 4; q++) {
        int id = tid + q * 256;               // 1024 chunks
        int n = id >> 5, ck = (id & 31) * 8;
        bf16x8 v = *(const bf16x8*)(ct + n * 264 + ck);
        *(bf16x8*)(y + ((size_t)b * NN + n0 + n) * NC + ck) = v;
    }
}

// ---------------- K1: QKV GEMM, 64x64 tiles. Q->qs[bh][n][d]; K,V->fragment-major --
// kf: per (bh, mt=m/16): 512-elem block; lane l elem (l*8+e) = K[m0 + (l&15)][ (l>>4)*8 + e ]
// vf: per (bh, mt):      512-elem block; elem (l*8 + dj*4 + e) = V[m0 + (l>>4)*4 + e][ dj*16 + (l&15) ]
__launch_bounds__(256)
__global__ void k_qkv(const __bf16* __restrict__ y, const __bf16* __restrict__ wb,
                      const float* __restrict__ bqkv,
                      const float* __restrict__ peqh, const float* __restrict__ peqw,
                      const float* __restrict__ pekh, const float* __restrict__ pekw,
                      const float* __restrict__ mm, const float* __restrict__ mb,
                      __bf16* __restrict__ qs, __bf16* __restrict__ kf, __bf16* __restrict__ vf) {
    __shared__ __bf16 smem[4][64 * 40];  // [a0 a1 b0 b1]; ct (64*72=4608) aliases smem[0..1]
    __bf16* ct = &smem[0][0];
    const int nt = blockIdx.x, ot = blockIdx.y, b = blockIdx.z;   // grid (64, 12, 2)
    const int tid = threadIdx.x;
    const int wave = tid >> 6, lane = tid & 63, ln = lane & 15, quad = lane >> 4;
    const int wm = (wave & 1) * 32, wn = (wave >> 1) * 32;
    floatx4 acc[2][2];
#pragma unroll
    for (int i = 0; i < 2; i++)
#pragma unroll
        for (int j = 0; j < 2; j++) acc[i][j] = 0.f;
    const __bf16* ysrc = y + ((size_t)b * NN + nt * 64) * NC;
    const __bf16* wsrc = wb + (size_t)ot * 64 * NC;
    const int r0 = tid >> 2, c0 = (tid & 3) * 8;
    bf16x8 ya[2], wa[2];
    ya[0] = *(const bf16x8*)(ysrc + (size_t)r0 * NC + c0);
    wa[0] = *(const bf16x8*)(wsrc + (size_t)r0 * NC + c0);
#pragma unroll 2
    for (int ko = 0; ko < 8; ko++) {
        int cur = ko & 1, nxt = cur ^ 1;
        *(bf16x8*)(&smem[cur][r0 * 40 + c0]) = ya[cur];
        *(bf16x8*)(&smem[2 + cur][r0 * 40 + c0]) = wa[cur];
        if (ko < 7) {                     // issue next-tile loads BEFORE the barrier
            int kc = (ko + 1) * 32;
            ya[nxt] = *(const bf16x8*)(ysrc + (size_t)r0 * NC + kc + c0);
            wa[nxt] = *(const bf16x8*)(wsrc + (size_t)r0 * NC + kc + c0);
        }
        __syncthreads();
        bf16x8 af[2], bfr[2];
#pragma unroll
        for (int ii = 0; ii < 2; ii++) af[ii]  = *(const bf16x8*)(&smem[cur][(wm + ii * 16 + ln) * 40 + quad * 8]);
#pragma unroll
        for (int jj = 0; jj < 2; jj++) bfr[jj] = *(const bf16x8*)(&smem[2 + cur][(wn + jj * 16 + ln) * 40 + quad * 8]);
#pragma unroll
        for (int ii = 0; ii < 2; ii++)
#pragma unroll
            for (int jj = 0; jj < 2; jj++)
                acc[ii][jj] = __builtin_amdgcn_mfma_f32_16x16x32_bf16(af[ii], bfr[jj], acc[ii][jj], 0, 0, 0);
    }
    __syncthreads();   // frag reads done before ct alias is written
    if (ot < 8) {
        // Q/K: ct[n_l][o_l]
#pragma unroll
        for (int ii = 0; ii < 2; ii++)
#pragma unroll
            for (int jj = 0; jj < 2; jj++) {
                int o_l = wn + jj * 16 + ln;
                int o_g = ot * 64 + o_l;
                float bq = bqkv[o_g];
#pragma unroll
                for (int r = 0; r < 4; r++) {
                    int n_l = wm + ii * 16 + quad * 4 + r;
                    float val = acc[ii][jj][r] + bq;
                    if (ot < 4) {         // Q: PE + FiLM + softmax scale
                        val += peqh[o_g * 64 + nt] + peqw[o_g * 64 + n_l];
                        val = val * mm[b * NF + o_g] + mb[b * NF + o_g];
                        val *= QSCALE;
                    } else {              // K: PE
                        int c = o_g - 256;
                        val += pekh[c * 64 + nt] + pekw[c * 64 + n_l];
                    }
                    ct[n_l * 72 + o_l] = (__bf16)val;
                }
            }
        __syncthreads();
#pragma unroll
        for (int q = 0; q < 2; q++) {
            int id = tid + q * 256;       // 512 chunks
            int n_l = id >> 3, oc = (id & 7) * 8;
            bf16x8 v = *(const bf16x8*)(ct + n_l * 72 + oc);
            int n_g = nt * 64 + n_l;
            int o_g = ot * 64 + oc;
            if (ot < 4) {
                int h = o_g >> 5, d = o_g & 31;
                *(bf16x8*)(qs + (((size_t)b * NH + h) * NN + n_g) * HSZ + d) = v;
            } else {
                int c = o_g - 256, h = c >> 5, d0 = c & 31;
                size_t blk = ((size_t)(b * NH + h) * 256 + (n_g >> 4)) * 512;
                *(bf16x8*)(kf + blk + (d0 >> 3) * 128 + (n_g & 15) * 8) = v;
            }
        }
    } else {
        // V: ct[o_l][n_l] -> vf fragment-major
#pragma unroll
        for (int ii = 0; ii < 2; ii++)
#pragma unroll
            for (int jj = 0; jj < 2; jj++) {
                int o_l = wn + jj * 16 + ln;
                float bq = bqkv[ot * 64 + o_l];
#pragma unroll
                for (int r = 0; r < 4; r++) {
                    int n_l = wm + ii * 16 + quad * 4 + r;
                    ct[o_l * 72 + n_l] = (__bf16)(acc[ii][jj][r] + bq);
                }
            }
        __syncthreads();
#pragma unroll
        for (int q = 0; q < 4; q++) {
            int id = tid + q * 256;       // 1024 slots of 4 elems
            int o_l = id >> 4, ng4 = (id & 15) * 4;
            bf16x4 v = *(const bf16x4*)(ct + o_l * 72 + ng4);
            int c = (ot - 8) * 64 + o_l, h = c >> 5, d = c & 31;
            int dj = d >> 4, lnv = d & 15;
            int m_g = nt * 64 + ng4;
            size_t blk = ((size_t)(b * NH + h) * 256 + (m_g >> 4)) * 512;
            *(bf16x4*)(vf + blk + (((m_g >> 2) & 3) * 16 + lnv) * 8 + dj * 4) = v;
        }
    }
}

// ---------------- K2: flash attention, split-K x4, dbuf DMA + counted vmcnt -------
// R6 (single-buf DMA + __syncthreads) = 56.6 us with ~40% issue-idle: every tile the
// barrier's implicit s_waitcnt vmcnt(0) exposed the full DMA round-trip. This version
// double-buffers at UNCHANGED 16 KB LDS (64-key tiles) and uses raw s_barrier with
// counted vmcnt: next tile's 2 DMA loads stay in flight across the barrier (T3/T4).
// Ledger: prologue issues 4 loads (tiles 0,1). Loop top waits vmcnt(2) -> tile mt
// landed, tile mt+1 in flight under compute. lgkmcnt(0)+barrier before buffer reuse.
__launch_bounds__(256, 8)
__global__ void k_attn(const __bf16* __restrict__ qs, const __bf16* __restrict__ kf,
                       const __bf16* __restrict__ vf,
                       __bf16* __restrict__ po012, __bf16* __restrict__ po3,
                       float* __restrict__ pl) {
    __shared__ __bf16 sbuf[2][4096];      // per buf: [kf 2048 | vf 2048] elems (16 KB)
    int bi = blockIdx.x;                  // 2048 blocks
    int xcd = bi & 7, r = bi >> 3;        // r: 0..255
    int bh = xcd * 2 + (r & 1);           // XCD owns 2 (b,h) pairs
    int r2 = r >> 1;                      // 0..127
    int qt = r2 & 31, piece = r2 >> 5;    // piece: 0..3 (1024 keys each)
    int tid = threadIdx.x, wave = tid >> 6, lane = tid & 63, ln = lane & 15, quad = lane >> 4;
    int n0 = qt * 128 + wave * 32;
    const __bf16* qbase = qs + (size_t)bh * NN * HSZ;
    const __bf16* kfb = kf + ((size_t)bh * 256 + piece * 64) * 512;
    const __bf16* vfb = vf + ((size_t)bh * 256 + piece * 64) * 512;
    bf16x8 qa[2];
    qa[0] = *(const bf16x8*)(qbase + (size_t)(n0 + ln) * HSZ + quad * 8);
    qa[1] = *(const bf16x8*)(qbase + (size_t)(n0 + 16 + ln) * HSZ + quad * 8);
    floatx4 o[2][2], o2[2];
    o[0][0] = 0.f; o[0][1] = 0.f; o[1][0] = 0.f; o[1][1] = 0.f;
    o2[0] = 0.f; o2[1] = 0.f;
    floatx4 zf = 0.f;
    s16x4 ones;
    ones[0] = (short)0x3F80; ones[1] = (short)0x3F80;
    ones[2] = (short)0x3F80; ones[3] = (short)0x3F80;   // bf16 1.0
    const int toff = tid * 8;             // staging: elems; tid*16 B -> DMA-legal linear
    const int lo = lane * 8;
    // prologue: tiles 0 (buf0) and 1 (buf1); 64-key tile = 2048 elems K + 2048 V
    GLD16(kfb + toff,        &sbuf[0][0] + toff);
    GLD16(vfb + toff,        &sbuf[0][0] + 2048 + toff);
    GLD16(kfb + 2048 + toff, &sbuf[1][0] + toff);
    GLD16(vfb + 2048 + toff, &sbuf[1][0] + 2048 + toff);
    for (int mt = 0; mt < 16; mt++) {     // 16 tiles x 64 keys = 1024 keys
        int cur = mt & 1;
        const __bf16* kl = &sbuf[0][0] + cur * 4096;
        const __bf16* vl = kl + 2048;
        if (mt < 15) asm volatile("s_waitcnt vmcnt(2)" ::: "memory");
        else         asm volatile("s_waitcnt vmcnt(0)" ::: "memory");
        __builtin_amdgcn_s_barrier();     // tile mt resident for all waves
        __builtin_amdgcn_s_setprio(1);
#pragma unroll
        for (int j = 0; j < 4; j++) {
            bf16x8 kfr = *(const bf16x8*)(kl + j * 512 + lo);
            bf16x8 vfr = *(const bf16x8*)(vl + j * 512 + lo);
            s16x4 vb0, vb1;
            __builtin_memcpy(&vb0, &vfr, 8);
            __builtin_memcpy(&vb1, (const char*)&vfr + 8, 8);
#pragma unroll
            for (int i = 0; i < 2; i++) {
                floatx4 s = __builtin_amdgcn_mfma_f32_16x16x32_bf16(kfr, qa[i], zf, 0, 0, 0);
                bf16x4 p;
#pragma unroll
                for (int rr = 0; rr < 4; rr++)
                    p[rr] = (__bf16)__builtin_amdgcn_exp2f(s[rr]);
                s16x4 pa;
                __builtin_memcpy(&pa, &p, 8);
                o[i][0] = __builtin_amdgcn_mfma_f32_16x16x16bf16_1k(pa, vb0, o[i][0], 0, 0, 0);
                o[i][1] = __builtin_amdgcn_mfma_f32_16x16x16bf16_1k(pa, vb1, o[i][1], 0, 0, 0);
                o2[i]   = __builtin_amdgcn_mfma_f32_16x16x16bf16_1k(pa, ones, o2[i], 0, 0, 0);
            }
        }
        __builtin_amdgcn_s_setprio(0);
        asm volatile("s_waitcnt lgkmcnt(0)" ::: "memory");  // my ds_reads complete
        __builtin_amdgcn_s_barrier();     // everyone done reading buf[cur]; NO vmcnt drain
        if (mt < 14) {                    // refill buf[cur] with tile mt+2
            const __bf16* kn = kfb + (size_t)(mt + 2) * 2048;
            const __bf16* vn = vfb + (size_t)(mt + 2) * 2048;
            GLD16(kn + toff, &sbuf[0][0] + cur * 4096 + toff);
            GLD16(vn + toff, &sbuf[0][0] + cur * 4096 + 2048 + toff);
        }
    }
    // epilogue: o2[i][r] = row-sum l for n = n0+i*16+quad*4+r (all lanes of quad agree)
    size_t plbase = (size_t)(piece * 16 + bh) * NN;
    if (ln == 0)
#pragma unroll
        for (int i = 0; i < 2; i++)
#pragma unroll
            for (int rr = 0; rr < 4; rr++)
                pl[plbase + n0 + i * 16 + quad * 4 + rr] = o2[i][rr];
    // po via LDS (waves write their own 32-row stripe of [128][32])
    __bf16* ct = &sbuf[0][0];             // 128*32 = 4096 elems
#pragma unroll
    for (int i = 0; i < 2; i++)
#pragma unroll
        for (int dj = 0; dj < 2; dj++)
#pragma unroll
            for (int rr = 0; rr < 4; rr++)
                ct[(wave * 32 + i * 16 + quad * 4 + rr) * 32 + dj * 16 + ln] = (__bf16)o[i][dj][rr];
    __syncthreads();
    __bf16* pob = (piece < 3) ? (po012 + (size_t)piece * PIECE) : po3;
    size_t pobase = ((size_t)bh * NN + (size_t)qt * 128) * HSZ;
#pragma unroll
    for (int q = 0; q < 2; q++) {
        int id = tid + q * 256;           // 512 chunks
        int n_l = id >> 2, dc = (id & 3) * 8;
        *(bf16x8*)(pob + pobase + n_l * HSZ + dc) = *(const bf16x8*)(ct + n_l * 32 + dc);
    }
}

// ---------------- K3: combine 4 partials + proj GEMM out[o,n] + residual ---------
// 64n x 32o tiles, grid (64, 8, 2) = 1024 blocks -> 4 blocks/CU, 16 waves/CU.
__launch_bounds__(256)
__global__ void k_proj(const __bf16* __restrict__ po012, const __bf16* __restrict__ po3,
                       const float* __restrict__ pl,
                       const __bf16* __restrict__ wpb, const float* __restrict__ ppb,
                       const float* __restrict__ x, const float* __restrict__ idsc,
                       float* __restrict__ out) {
    __shared__ __bf16 at[32 * 264];    // w_proj tile [32 o][256 f]
    __shared__ __bf16 bt[2][64 * 40];  // combined attn tile [64 n][32 f]
    __shared__ float linv[8 * 64];
    __shared__ float ppbs[256];
    int nt = blockIdx.x, ot = blockIdx.y, b = blockIdx.z;   // grid (64, 8, 2)
    int tid = threadIdx.x, wave = tid >> 6, lane = tid & 63, ln = lane & 15, quad = lane >> 4;
    int wo = (wave & 1) * 16, wn = (wave >> 1) * 32;
#pragma unroll
    for (int q = 0; q < 4; q++) {
        int id = tid + q * 256;           // 1024 chunks: 32 rows x 32 f-chunks
        int row = id >> 5, fc = (id & 31) * 8;
        *(bf16x8*)(at + row * 264 + fc) = *(const bf16x8*)(wpb + (size_t)(ot * 32 + row) * NF + fc);
    }
#pragma unroll
    for (int q = 0; q < 2; q++) {
        int id = tid + q * 256;           // 512 = 8h x 64n
        int h = id >> 6, n_l = id & 63;
        size_t base = (size_t)(b * NH + h) * NN + nt * 64 + n_l;
        linv[id] = 1.f / (pl[base] + pl[base + (size_t)16 * NN]
                        + pl[base + (size_t)32 * NN] + pl[base + (size_t)48 * NN]);
    }
    ppbs[tid] = ppb[tid];
    __syncthreads();
    floatx4 acc[2];
    acc[0] = 0.f; acc[1] = 0.f;
    const int n_l = tid >> 2, dh8 = (tid & 3) * 8;
    const size_t hstep = (size_t)NN * HSZ;
    size_t prow = ((size_t)b * NH * NN + (size_t)nt * 64 + n_l) * HSZ + dh8;
    bf16x8 p0[2], p1[2], p2[2], p3[2];
    p0[0] = *(const bf16x8*)(po012 + prow);
    p1[0] = *(const bf16x8*)(po012 + prow + (size_t)PIECE);
    p2[0] = *(const bf16x8*)(po012 + prow + (size_t)2 * PIECE);
    p3[0] = *(const bf16x8*)(po3 + prow);
#pragma unroll 2
    for (int ko = 0; ko < 8; ko++) {
        int cur = ko & 1, nxt = cur ^ 1;
        float iv = linv[ko * 64 + n_l];
        bf16x8 c;
#pragma unroll
        for (int e = 0; e < 8; e++)
            c[e] = (__bf16)(((float)p0[cur][e] + (float)p1[cur][e]
                           + (float)p2[cur][e] + (float)p3[cur][e]) * iv
                           + ppbs[ko * 32 + dh8 + e]);
        *(bf16x8*)(&bt[cur][n_l * 40 + dh8]) = c;
        if (ko < 7) {                     // issue next-slab loads BEFORE the barrier
            size_t pr = prow + (size_t)(ko + 1) * hstep;
            p0[nxt] = *(const bf16x8*)(po012 + pr);
            p1[nxt] = *(const bf16x8*)(po012 + pr + (size_t)PIECE);
            p2[nxt] = *(const bf16x8*)(po012 + pr + (size_t)2 * PIECE);
            p3[nxt] = *(const bf16x8*)(po3 + pr);
        }
        __syncthreads();
        bf16x8 af, bfr[2];
        af = *(const bf16x8*)(at + (wo + ln) * 264 + ko * 32 + quad * 8);
#pragma unroll
        for (int nj = 0; nj < 2; nj++) bfr[nj] = *(const bf16x8*)(&bt[cur][(wn + nj * 16 + ln) * 40 + quad * 8]);
#pragma unroll
        for (int nj = 0; nj < 2; nj++)
            acc[nj] = __builtin_amdgcn_mfma_f32_16x16x32_bf16(af, bfr[nj], acc[nj], 0, 0, 0);
    }
#pragma unroll
    for (int nj = 0; nj < 2; nj++)
#pragma unroll
        for (int r = 0; r < 4; r++) {
            int o_g = ot * 32 + wo + quad * 4 + r;
            int n_g = nt * 64 + wn + nj * 16 + ln;
            size_t idx = ((size_t)b * NF + o_g) * NN + n_g;
            out[idx] = x[idx] * idsc[o_g] + acc[nj][r];
        }
}

// ---------------- launcher ----------------
extern "C" void kernel_launch(void* const* d_in, const int* in_sizes, int n_in,
                              void* d_out, int out_size, void* d_ws, size_t ws_size,
                              hipStream_t stream) {
    (void)in_sizes; (void)n_in; (void)out_size; (void)ws_size;
    const float* x    = (const float*)d_in[0];
    const float* mm   = (const float*)d_in[1];
    const float* mb   = (const float*)d_in[2];
    const float* wqkv = (const float*)d_in[3];
    const float* bqkv = (const float*)d_in[4];
    const float* wproj= (const float*)d_in[5];
    const float* peqh = (const float*)d_in[6];
    const float* peqw = (const float*)d_in[7];
    const float* pekh = (const float*)d_in[8];
    const float* pekw = (const float*)d_in[9];
    const float* pab  = (const float*)d_in[10];
    const float* pqb  = (const float*)d_in[11];
    const float* ppb  = (const float*)d_in[12];
    const float* idsc = (const float*)d_in[13];
    float* out = (float*)d_out;

    __bf16* ws = (__bf16*)d_ws;
    const size_t SEG = 2097152;            // elements per big buffer
    __bf16* y     = ws;                    // SEG0; dead after k_qkv -> reused as po piece 3
    __bf16* qs    = ws + SEG;
    __bf16* kf    = ws + SEG * 2;
    __bf16* vf    = ws + SEG * 3;
    __bf16* po012 = ws + SEG * 4;          // pieces 0..2 (1 SEG each)
    __bf16* po3   = ws;                    // aliases y
    float*  pl    = (float*)(ws + SEG * 7); // 262144 floats (4 pieces x 16bh x 4096)
    __bf16* wqb   = ws + SEG * 7 + 524288;
    __bf16* wpb   = wqb + 196608;

    hipLaunchKernelGGL(k_prep, dim3(512), dim3(256), 0, stream,
                       x, pab, pqb, y, wqkv, wproj, wqb, wpb);
    hipLaunchKernelGGL(k_qkv,  dim3(64, 12, 2), dim3(256), 0, stream,
                       y, wqb, bqkv, peqh, peqw, pekh, pekw, mm, mb, qs, kf, vf);
    hipLaunchKernelGGL(k_attn, dim3(2048), dim3(256), 0, stream,
                       qs, kf, vf, po012, po3, pl);
    hipLaunchKernelGGL(k_proj, dim3(64, 8, 2), dim3(256), 0, stream,
                       po012, po3, pl, wpb, ppb, x, idsc, out);
}

// Round 8
// 159.458 us; speedup vs baseline: 1.0535x; 1.0535x over previous
//
#include <hip/hip_runtime.h>
#include <hip/hip_bf16.h>
#include <cstdint>

// Problem constants
#define NB   2
#define NC   256
#define NN   4096   // H*W = 64*64
#define NH   8      // heads
#define HSZ  32     // head size
#define NF   256    // FEAT
#define N3F  768

typedef __bf16 bf16x8 __attribute__((ext_vector_type(8)));
typedef __bf16 bf16x4 __attribute__((ext_vector_type(4)));
typedef short  s16x4  __attribute__((ext_vector_type(4)));
typedef float  floatx4 __attribute__((ext_vector_type(4)));

// log2(e)/sqrt(32): folded into q so softmax runs in exp2 domain
#define QSCALE 0.25506601622184f

// po piece stride: 16 bh x 4096 n x 32 d
#define PIECE 2097152

// direct global->LDS DMA, 16 B per lane (dest must be wave-uniform base + lane*16)
#define GLD16(gsrc, ldst)                                                             \
    __builtin_amdgcn_global_load_lds(                                                 \
        (const __attribute__((address_space(1))) unsigned int*)(gsrc),                \
        (__attribute__((address_space(3))) unsigned int*)(ldst), 16, 0, 0)

// ---------------- K0: prep = preact silu (blocks 0..255) + weight cvt (256..511) --
__global__ void k_prep(const float* __restrict__ x, const float* __restrict__ pab,
                       const float* __restrict__ pqb, __bf16* __restrict__ y,
                       const float* __restrict__ wqkv, const float* __restrict__ wproj,
                       __bf16* __restrict__ wqb, __bf16* __restrict__ wpb) {
    __shared__ __bf16 ct[32 * 264];           // [n][c], stride 264
    int bid = blockIdx.x, tid = threadIdx.x;
    if (bid >= 256) {                         // weight convert: 4 elems/thread
        int id = (bid - 256) * 1024 + tid * 4;
        const float* src = (id < 196608) ? (wqkv + id) : (wproj + (id - 196608));
        __bf16* dst = (id < 196608) ? (wqb + id) : (wpb + (id - 196608));
        float4 v = *(const float4*)src;
        bf16x4 o;
        o[0] = (__bf16)v.x; o[1] = (__bf16)v.y; o[2] = (__bf16)v.z; o[3] = (__bf16)v.w;
        *(bf16x4*)dst = o;
        return;
    }
    int b = bid >> 7, nt = bid & 127;
    int n0 = nt * 32;
    int cbase = tid >> 3, nc = tid & 7;       // n-chunk nc covers 4 n
#pragma unroll
    for (int q = 0; q < 8; q++) {
        int c = cbase + q * 32;
        const float4 xv = *(const float4*)(x + ((size_t)b * NC + c) * NN + n0 + nc * 4);
        float bias = pab[c], qb = pqb[c];
        float vs[4] = {xv.x, xv.y, xv.z, xv.w};
#pragma unroll
        for (int i = 0; i < 4; i++) {
            float s = vs[i] + bias;
            float r = s / (1.f + __expf(-s)) + qb;   // silu + pre_qkv_bias
            ct[(nc * 4 + i) * 264 + c] = (__bf16)r;
        }
    }
    __syncthreads();
#pragma unroll
    for (int q = 0; q < 4; q++) {
        int id = tid + q * 256;               // 1024 chunks
        int n = id >> 5, ck = (id & 31) * 8;
        bf16x8 v = *(const bf16x8*)(ct + n * 264 + ck);
        *(bf16x8*)(y + ((size_t)b * NN + n0 + n) * NC + ck) = v;
    }
}

// ---------------- K1: QKV GEMM, 64x64 tiles. Q->qs[bh][n][d]; K,V->fragment-major --
// kf: per (bh, mt=m/16): 512-elem block; lane l elem (l*8+e) = K[m0 + (l&15)][ (l>>4)*8 + e ]
// vf: per (bh, mt):      512-elem block; elem (l*8 + dj*4 + e) = V[m0 + (l>>4)*4 + e][ dj*16 + (l&15) ]
// R8: epilogue PE/FiLM/bias loads hoisted+vectorized (was ~40 scalar scattered
// global loads per thread inside the per-element loop; now ~12 mostly-float4 loads
// issued together, Q/K epilogue unified into one FMA form).
__launch_bounds__(256)
__global__ void k_qkv(const __bf16* __restrict__ y, const __bf16* __restrict__ wb,
                      const float* __restrict__ bqkv,
                      const float* __restrict__ peqh, const float* __restrict__ peqw,
                      const float* __restrict__ pekh, const float* __restrict__ pekw,
                      const float* __restrict__ mm, const float* __restrict__ mb,
                      __bf16* __restrict__ qs, __bf16* __restrict__ kf, __bf16* __restrict__ vf) {
    __shared__ __bf16 smem[4][64 * 40];  // [a0 a1 b0 b1]; ct (64*72=4608) aliases smem[0..1]
    __bf16* ct = &smem[0][0];
    const int nt = blockIdx.x, ot = blockIdx.y, b = blockIdx.z;   // grid (64, 12, 2)
    const int tid = threadIdx.x;
    const int wave = tid >> 6, lane = tid & 63, ln = lane & 15, quad = lane >> 4;
    const int wm = (wave & 1) * 32, wn = (wave >> 1) * 32;
    floatx4 acc[2][2];
#pragma unroll
    for (int i = 0; i < 2; i++)
#pragma unroll
        for (int j = 0; j < 2; j++) acc[i][j] = 0.f;
    const __bf16* ysrc = y + ((size_t)b * NN + nt * 64) * NC;
    const __bf16* wsrc = wb + (size_t)ot * 64 * NC;
    const int r0 = tid >> 2, c0 = (tid & 3) * 8;
    bf16x8 ya[2], wa[2];
    ya[0] = *(const bf16x8*)(ysrc + (size_t)r0 * NC + c0);
    wa[0] = *(const bf16x8*)(wsrc + (size_t)r0 * NC + c0);
#pragma unroll 2
    for (int ko = 0; ko < 8; ko++) {
        int cur = ko & 1, nxt = cur ^ 1;
        *(bf16x8*)(&smem[cur][r0 * 40 + c0]) = ya[cur];
        *(bf16x8*)(&smem[2 + cur][r0 * 40 + c0]) = wa[cur];
        if (ko < 7) {                     // issue next-tile loads BEFORE the barrier
            int kc = (ko + 1) * 32;
            ya[nxt] = *(const bf16x8*)(ysrc + (size_t)r0 * NC + kc + c0);
            wa[nxt] = *(const bf16x8*)(wsrc + (size_t)r0 * NC + kc + c0);
        }
        __syncthreads();
        bf16x8 af[2], bfr[2];
#pragma unroll
        for (int ii = 0; ii < 2; ii++) af[ii]  = *(const bf16x8*)(&smem[cur][(wm + ii * 16 + ln) * 40 + quad * 8]);
#pragma unroll
        for (int jj = 0; jj < 2; jj++) bfr[jj] = *(const bf16x8*)(&smem[2 + cur][(wn + jj * 16 + ln) * 40 + quad * 8]);
#pragma unroll
        for (int ii = 0; ii < 2; ii++)
#pragma unroll
            for (int jj = 0; jj < 2; jj++)
                acc[ii][jj] = __builtin_amdgcn_mfma_f32_16x16x32_bf16(af[ii], bfr[jj], acc[ii][jj], 0, 0, 0);
    }
    __syncthreads();   // frag reads done before ct alias is written
    const int o_lA = wn + ln, o_lB = o_lA + 16;   // jj=0 / jj=1 output columns
    const int o_gA = ot * 64 + o_lA, o_gB = ot * 64 + o_lB;
    const float bqA = bqkv[o_gA], bqB = bqkv[o_gB];
    if (ot < 8) {
        // Hoisted, vectorized epilogue parameters (Q: PE+FiLM+QSCALE; K: PE only).
        float phA, phB, mmA, mmB, mbA, mbB;
        float4 pw[2][2];                  // [jj][ii], elem r = PE_w for n_l=wm+ii*16+quad*4+r
        if (ot < 4) {
            phA = peqh[o_gA * 64 + nt]; phB = peqh[o_gB * 64 + nt];
            pw[0][0] = *(const float4*)(peqw + o_gA * 64 + wm + quad * 4);
            pw[0][1] = *(const float4*)(peqw + o_gA * 64 + wm + 16 + quad * 4);
            pw[1][0] = *(const float4*)(peqw + o_gB * 64 + wm + quad * 4);
            pw[1][1] = *(const float4*)(peqw + o_gB * 64 + wm + 16 + quad * 4);
            mmA = mm[b * NF + o_gA] * QSCALE; mmB = mm[b * NF + o_gB] * QSCALE;
            mbA = mb[b * NF + o_gA] * QSCALE; mbB = mb[b * NF + o_gB] * QSCALE;
        } else {
            int cA = o_gA - 256, cB = o_gB - 256;
            phA = pekh[cA * 64 + nt]; phB = pekh[cB * 64 + nt];
            pw[0][0] = *(const float4*)(pekw + cA * 64 + wm + quad * 4);
            pw[0][1] = *(const float4*)(pekw + cA * 64 + wm + 16 + quad * 4);
            pw[1][0] = *(const float4*)(pekw + cB * 64 + wm + quad * 4);
            pw[1][1] = *(const float4*)(pekw + cB * 64 + wm + 16 + quad * 4);
            mmA = 1.f; mmB = 1.f; mbA = 0.f; mbB = 0.f;   // K: identity FiLM, no QSCALE
        }
        float pwv[2][2][4];
#pragma unroll
        for (int jj = 0; jj < 2; jj++)
#pragma unroll
            for (int ii = 0; ii < 2; ii++) {
                pwv[jj][ii][0] = pw[jj][ii].x; pwv[jj][ii][1] = pw[jj][ii].y;
                pwv[jj][ii][2] = pw[jj][ii].z; pwv[jj][ii][3] = pw[jj][ii].w;
            }
        // Q/K unified: ct[n_l][o_l] = (acc + bq + ph + pw) * mm' + mb'
#pragma unroll
        for (int ii = 0; ii < 2; ii++)
#pragma unroll
            for (int jj = 0; jj < 2; jj++) {
                int o_l = jj ? o_lB : o_lA;
                float bq = jj ? bqB : bqA, ph = jj ? phB : phA;
                float mmv = jj ? mmB : mmA, mbv = jj ? mbB : mbA;
#pragma unroll
                for (int r = 0; r < 4; r++) {
                    int n_l = wm + ii * 16 + quad * 4 + r;
                    float val = (acc[ii][jj][r] + bq + ph + pwv[jj][ii][r]) * mmv + mbv;
                    ct[n_l * 72 + o_l] = (__bf16)val;
                }
            }
        __syncthreads();
#pragma unroll
        for (int q = 0; q < 2; q++) {
            int id = tid + q * 256;       // 512 chunks
            int n_l = id >> 3, oc = (id & 7) * 8;
            bf16x8 v = *(const bf16x8*)(ct + n_l * 72 + oc);
            int n_g = nt * 64 + n_l;
            int o_g = ot * 64 + oc;
            if (ot < 4) {
                int h = o_g >> 5, d = o_g & 31;
                *(bf16x8*)(qs + (((size_t)b * NH + h) * NN + n_g) * HSZ + d) = v;
            } else {
                int c = o_g - 256, h = c >> 5, d0 = c & 31;
                size_t blk = ((size_t)(b * NH + h) * 256 + (n_g >> 4)) * 512;
                *(bf16x8*)(kf + blk + (d0 >> 3) * 128 + (n_g & 15) * 8) = v;
            }
        }
    } else {
        // V: ct[o_l][n_l] -> vf fragment-major
#pragma unroll
        for (int ii = 0; ii < 2; ii++)
#pragma unroll
            for (int jj = 0; jj < 2; jj++) {
                int o_l = jj ? o_lB : o_lA;
                float bq = jj ? bqB : bqA;
#pragma unroll
                for (int r = 0; r < 4; r++) {
                    int n_l = wm + ii * 16 + quad * 4 + r;
                    ct[o_l * 72 + n_l] = (__bf16)(acc[ii][jj][r] + bq);
                }
            }
        __syncthreads();
#pragma unroll
        for (int q = 0; q < 4; q++) {
            int id = tid + q * 256;       // 1024 slots of 4 elems
            int o_l = id >> 4, ng4 = (id & 15) * 4;
            bf16x4 v = *(const bf16x4*)(ct + o_l * 72 + ng4);
            int c = (ot - 8) * 64 + o_l, h = c >> 5, d = c & 31;
            int dj = d >> 4, lnv = d & 15;
            int m_g = nt * 64 + ng4;
            size_t blk = ((size_t)(b * NH + h) * 256 + (m_g >> 4)) * 512;
            *(bf16x4*)(vf + blk + (((m_g >> 2) & 3) * 16 + lnv) * 8 + dj * 4) = v;
        }
    }
}

// ---------------- K2: flash attention, split-K x4, global_load_lds staging --------
// R6 structure (best measured: 56.6 us). R7's counted-vmcnt dbuf regressed (58.6):
// barrier count doubled and the drain wasn't the stall — 8 blocks/CU TLP already
// covers DMA latency. Keep: single 16 KB buffer, 128-key tiles, __syncthreads.
__launch_bounds__(256, 8)
__global__ void k_attn(const __bf16* __restrict__ qs, const __bf16* __restrict__ kf,
                       const __bf16* __restrict__ vf,
                       __bf16* __restrict__ po012, __bf16* __restrict__ po3,
                       float* __restrict__ pl) {
    __shared__ __bf16 sbuf[8192];         // [kf 4096 | vf 4096] elems, single buffer
    int bi = blockIdx.x;                  // 2048 blocks
    int xcd = bi & 7, r = bi >> 3;        // r: 0..255
    int bh = xcd * 2 + (r & 1);           // XCD owns 2 (b,h) pairs
    int r2 = r >> 1;                      // 0..127
    int qt = r2 & 31, piece = r2 >> 5;    // piece: 0..3 (1024 keys each)
    int tid = threadIdx.x, wave = tid >> 6, lane = tid & 63, ln = lane & 15, quad = lane >> 4;
    int n0 = qt * 128 + wave * 32;
    const __bf16* qbase = qs + (size_t)bh * NN * HSZ;
    const __bf16* kfb = kf + ((size_t)bh * 256 + piece * 64) * 512;
    const __bf16* vfb = vf + ((size_t)bh * 256 + piece * 64) * 512;
    bf16x8 qa[2];
    qa[0] = *(const bf16x8*)(qbase + (size_t)(n0 + ln) * HSZ + quad * 8);
    qa[1] = *(const bf16x8*)(qbase + (size_t)(n0 + 16 + ln) * HSZ + quad * 8);
    floatx4 o[2][2], o2[2];
    o[0][0] = 0.f; o[0][1] = 0.f; o[1][0] = 0.f; o[1][1] = 0.f;
    o2[0] = 0.f; o2[1] = 0.f;
    floatx4 zf = 0.f;
    s16x4 ones;
    ones[0] = (short)0x3F80; ones[1] = (short)0x3F80;
    ones[2] = (short)0x3F80; ones[3] = (short)0x3F80;   // bf16 1.0
    const int toff = tid * 8;             // staging: elems; tid*16 B -> DMA-legal linear
    const int lo = lane * 8;
    for (int mt = 0; mt < 8; mt++) {      // 8 tiles x 128 keys = 1024 keys
        const __bf16* kn = kfb + mt * 4096;
        const __bf16* vn = vfb + mt * 4096;
        GLD16(kn + toff,        sbuf + toff);
        GLD16(kn + toff + 2048, sbuf + toff + 2048);
        GLD16(vn + toff,        sbuf + 4096 + toff);
        GLD16(vn + toff + 2048, sbuf + 4096 + toff + 2048);
        __syncthreads();                  // drains vmcnt (DMA done) + all waves synced
        __builtin_amdgcn_s_setprio(1);
#pragma unroll
        for (int j = 0; j < 8; j++) {
            bf16x8 kfr = *(const bf16x8*)(sbuf + j * 512 + lo);
            bf16x8 vfr = *(const bf16x8*)(sbuf + 4096 + j * 512 + lo);
            s16x4 vb0, vb1;
            __builtin_memcpy(&vb0, &vfr, 8);
            __builtin_memcpy(&vb1, (const char*)&vfr + 8, 8);
#pragma unroll
            for (int i = 0; i < 2; i++) {
                floatx4 s = __builtin_amdgcn_mfma_f32_16x16x32_bf16(kfr, qa[i], zf, 0, 0, 0);
                bf16x4 p;
#pragma unroll
                for (int rr = 0; rr < 4; rr++)
                    p[rr] = (__bf16)__builtin_amdgcn_exp2f(s[rr]);
                s16x4 pa;
                __builtin_memcpy(&pa, &p, 8);
                o[i][0] = __builtin_amdgcn_mfma_f32_16x16x16bf16_1k(pa, vb0, o[i][0], 0, 0, 0);
                o[i][1] = __builtin_amdgcn_mfma_f32_16x16x16bf16_1k(pa, vb1, o[i][1], 0, 0, 0);
                o2[i]   = __builtin_amdgcn_mfma_f32_16x16x16bf16_1k(pa, ones, o2[i], 0, 0, 0);
            }
        }
        __builtin_amdgcn_s_setprio(0);
        __syncthreads();                  // all reads done before next DMA overwrite
    }
    // epilogue: o2[i][r] = row-sum l for n = n0+i*16+quad*4+r (all lanes of quad agree)
    size_t plbase = (size_t)(piece * 16 + bh) * NN;
    if (ln == 0)
#pragma unroll
        for (int i = 0; i < 2; i++)
#pragma unroll
            for (int rr = 0; rr < 4; rr++)
                pl[plbase + n0 + i * 16 + quad * 4 + rr] = o2[i][rr];
    // po via LDS (waves write their own 32-row stripe of [128][32])
    __bf16* ct = sbuf;                    // 128*32 = 4096 elems
#pragma unroll
    for (int i = 0; i < 2; i++)
#pragma unroll
        for (int dj = 0; dj < 2; dj++)
#pragma unroll
            for (int rr = 0; rr < 4; rr++)
                ct[(wave * 32 + i * 16 + quad * 4 + rr) * 32 + dj * 16 + ln] = (__bf16)o[i][dj][rr];
    __syncthreads();
    __bf16* pob = (piece < 3) ? (po012 + (size_t)piece * PIECE) : po3;
    size_t pobase = ((size_t)bh * NN + (size_t)qt * 128) * HSZ;
#pragma unroll
    for (int q = 0; q < 2; q++) {
        int id = tid + q * 256;           // 512 chunks
        int n_l = id >> 2, dc = (id & 3) * 8;
        *(bf16x8*)(pob + pobase + n_l * HSZ + dc) = *(const bf16x8*)(ct + n_l * 32 + dc);
    }
}

// ---------------- K3: combine 4 partials + proj GEMM out[o,n] + residual ---------
// 64n x 32o tiles, grid (64, 8, 2) = 1024 blocks -> 4 blocks/CU, 16 waves/CU.
__launch_bounds__(256)
__global__ void k_proj(const __bf16* __restrict__ po012, const __bf16* __restrict__ po3,
                       const float* __restrict__ pl,
                       const __bf16* __restrict__ wpb, const float* __restrict__ ppb,
                       const float* __restrict__ x, const float* __restrict__ idsc,
                       float* __restrict__ out) {
    __shared__ __bf16 at[32 * 264];    // w_proj tile [32 o][256 f]
    __shared__ __bf16 bt[2][64 * 40];  // combined attn tile [64 n][32 f]
    __shared__ float linv[8 * 64];
    __shared__ float ppbs[256];
    int nt = blockIdx.x, ot = blockIdx.y, b = blockIdx.z;   // grid (64, 8, 2)
    int tid = threadIdx.x, wave = tid >> 6, lane = tid & 63, ln = lane & 15, quad = lane >> 4;
    int wo = (wave & 1) * 16, wn = (wave >> 1) * 32;
#pragma unroll
    for (int q = 0; q < 4; q++) {
        int id = tid + q * 256;           // 1024 chunks: 32 rows x 32 f-chunks
        int row = id >> 5, fc = (id & 31) * 8;
        *(bf16x8*)(at + row * 264 + fc) = *(const bf16x8*)(wpb + (size_t)(ot * 32 + row) * NF + fc);
    }
#pragma unroll
    for (int q = 0; q < 2; q++) {
        int id = tid + q * 256;           // 512 = 8h x 64n
        int h = id >> 6, n_l = id & 63;
        size_t base = (size_t)(b * NH + h) * NN + nt * 64 + n_l;
        linv[id] = 1.f / (pl[base] + pl[base + (size_t)16 * NN]
                        + pl[base + (size_t)32 * NN] + pl[base + (size_t)48 * NN]);
    }
    ppbs[tid] = ppb[tid];
    __syncthreads();
    floatx4 acc[2];
    acc[0] = 0.f; acc[1] = 0.f;
    const int n_l = tid >> 2, dh8 = (tid & 3) * 8;
    const size_t hstep = (size_t)NN * HSZ;
    size_t prow = ((size_t)b * NH * NN + (size_t)nt * 64 + n_l) * HSZ + dh8;
    bf16x8 p0[2], p1[2], p2[2], p3[2];
    p0[0] = *(const bf16x8*)(po012 + prow);
    p1[0] = *(const bf16x8*)(po012 + prow + (size_t)PIECE);
    p2[0] = *(const bf16x8*)(po012 + prow + (size_t)2 * PIECE);
    p3[0] = *(const bf16x8*)(po3 + prow);
#pragma unroll 2
    for (int ko = 0; ko < 8; ko++) {
        int cur = ko & 1, nxt = cur ^ 1;
        float iv = linv[ko * 64 + n_l];
        bf16x8 c;
#pragma unroll
        for (int e = 0; e < 8; e++)
            c[e] = (__bf16)(((float)p0[cur][e] + (float)p1[cur][e]
                           + (float)p2[cur][e] + (float)p3[cur][e]) * iv
                           + ppbs[ko * 32 + dh8 + e]);
        *(bf16x8*)(&bt[cur][n_l * 40 + dh8]) = c;
        if (ko < 7) {                     // issue next-slab loads BEFORE the barrier
            size_t pr = prow + (size_t)(ko + 1) * hstep;
            p0[nxt] = *(const bf16x8*)(po012 + pr);
            p1[nxt] = *(const bf16x8*)(po012 + pr + (size_t)PIECE);
            p2[nxt] = *(const bf16x8*)(po012 + pr + (size_t)2 * PIECE);
            p3[nxt] = *(const bf16x8*)(po3 + pr);
        }
        __syncthreads();
        bf16x8 af, bfr[2];
        af = *(const bf16x8*)(at + (wo + ln) * 264 + ko * 32 + quad * 8);
#pragma unroll
        for (int nj = 0; nj < 2; nj++) bfr[nj] = *(const bf16x8*)(&bt[cur][(wn + nj * 16 + ln) * 40 + quad * 8]);
#pragma unroll
        for (int nj = 0; nj < 2; nj++)
            acc[nj] = __builtin_amdgcn_mfma_f32_16x16x32_bf16(af, bfr[nj], acc[nj], 0, 0, 0);
    }
#pragma unroll
    for (int nj = 0; nj < 2; nj++)
#pragma unroll
        for (int r = 0; r < 4; r++) {
            int o_g = ot * 32 + wo + quad * 4 + r;
            int n_g = nt * 64 + wn + nj * 16 + ln;
            size_t idx = ((size_t)b * NF + o_g) * NN + n_g;
            out[idx] = x[idx] * idsc[o_g] + acc[nj][r];
        }
}

// ---------------- launcher ----------------
extern "C" void kernel_launch(void* const* d_in, const int* in_sizes, int n_in,
                              void* d_out, int out_size, void* d_ws, size_t ws_size,
                              hipStream_t stream) {
    (void)in_sizes; (void)n_in; (void)out_size; (void)ws_size;
    const float* x    = (const float*)d_in[0];
    const float* mm   = (const float*)d_in[1];
    const float* mb   = (const float*)d_in[2];
    const float* wqkv = (const float*)d_in[3];
    const float* bqkv = (const float*)d_in[4];
    const float* wproj= (const float*)d_in[5];
    const float* peqh = (const float*)d_in[6];
    const float* peqw = (const float*)d_in[7];
    const float* pekh = (const float*)d_in[8];
    const float* pekw = (const float*)d_in[9];
    const float* pab  = (const float*)d_in[10];
    const float* pqb  = (const float*)d_in[11];
    const float* ppb  = (const float*)d_in[12];
    const float* idsc = (const float*)d_in[13];
    float* out = (float*)d_out;

    __bf16* ws = (__bf16*)d_ws;
    const size_t SEG = 2097152;            // elements per big buffer
    __bf16* y     = ws;                    // SEG0; dead after k_qkv -> reused as po piece 3
    __bf16* qs    = ws + SEG;
    __bf16* kf    = ws + SEG * 2;
    __bf16* vf    = ws + SEG * 3;
    __bf16* po012 = ws + SEG * 4;          // pieces 0..2 (1 SEG each)
    __bf16* po3   = ws;                    // aliases y
    float*  pl    = (float*)(ws + SEG * 7); // 262144 floats (4 pieces x 16bh x 4096)
    __bf16* wqb   = ws + SEG * 7 + 524288;
    __bf16* wpb   = wqb + 196608;

    hipLaunchKernelGGL(k_prep, dim3(512), dim3(256), 0, stream,
                       x, pab, pqb, y, wqkv, wproj, wqb, wpb);
    hipLaunchKernelGGL(k_qkv,  dim3(64, 12, 2), dim3(256), 0, stream,
                       y, wqb, bqkv, peqh, peqw, pekh, pekw, mm, mb, qs, kf, vf);
    hipLaunchKernelGGL(k_attn, dim3(2048), dim3(256), 0, stream,
                       qs, kf, vf, po012, po3, pl);
    hipLaunchKernelGGL(k_proj, dim3(64, 8, 2), dim3(256), 0, stream,
                       po012, po3, pl, wpb, ppb, x, idsc, out);
}